// Round 16
// baseline (140.950 us; speedup 1.0000x reference)
//
#include <hip/hip_runtime.h>
#include <hip/hip_bf16.h>

// ---------------------------------------------------------------------------
// BehaviorSpecificPFF: token-routed 4-expert FFN.
//   y[tok] = relu(x[tok] @ W1[g] + B1[g]) @ W2[g] + B2[g],  g = b_seq[tok]-1
//   b_seq==0 -> zeros.
// Round 16: GEMM1 -> 256x256 tile, BK=64, 1024 threads = 16 waves (4m x 4n),
// T4 counted depth-2 pipeline, 128KB LDS dbuf. Gets BOTH remaining levers:
// staged bytes 426->270MB AND wave residency 8->16 waves/CU. No packing
// changes (256-tile = 2 consecutive packed 16KB blocks on each side).
// GEMM2 kept byte-for-byte at r15 (proven 53us) for a clean A/B.
// ---------------------------------------------------------------------------

typedef short s16x8 __attribute__((ext_vector_type(8)));
typedef float f32x4 __attribute__((ext_vector_type(4)));

#define NTOK   16384
#define HDIM   512
#define FDIM   2048
#define NEXP   4
#define MAXMT  132   // worst-case total 128-row m-tiles (4 experts)

// ---- header layout (ints) in ws ----
// [0..3] counts  [4..7] cursors  [8..12] token offsets ([12]=total)
// [13..17] gemm1 128-tile bases (xa mtile base = hdr[13+g]>>4)
// [18..22] gemm2 tile bases (Hp mtile base = hdr[18+g]>>2) ([22]=total2)
// [23..27] gemm1 256x256 tile bases ([27]=total1)

__global__ void k_init(const int* __restrict__ b_seq,
                       float4* __restrict__ out, int n4) {
  float4 z; z.x = z.y = z.z = z.w = 0.f;
  for (int i = blockIdx.x * blockDim.x + threadIdx.x; i < n4;
       i += gridDim.x * blockDim.x) {
    // non-pad out rows are fully rewritten by GEMM2 every call; only padding
    // rows need zeros (out float4-row token = i>>7).
    if (b_seq[i >> 7] == 0) out[i] = z;
  }
}

__global__ void k_count_scan(const int4* __restrict__ b4,
                             int* __restrict__ hdr) {
  __shared__ int cnt[4];
  if (threadIdx.x < 4) cnt[threadIdx.x] = 0;
  __syncthreads();
  int c0 = 0, c1 = 0, c2 = 0, c3 = 0;
  for (int i = threadIdx.x; i < NTOK / 4; i += 1024) {
    int4 v = b4[i];
    c0 += (v.x == 1) + (v.y == 1) + (v.z == 1) + (v.w == 1);
    c1 += (v.x == 2) + (v.y == 2) + (v.z == 2) + (v.w == 2);
    c2 += (v.x == 3) + (v.y == 3) + (v.z == 3) + (v.w == 3);
    c3 += (v.x == 4) + (v.y == 4) + (v.z == 4) + (v.w == 4);
  }
  if (c0) atomicAdd(&cnt[0], c0);
  if (c1) atomicAdd(&cnt[1], c1);
  if (c2) atomicAdd(&cnt[2], c2);
  if (c3) atomicAdd(&cnt[3], c3);
  __syncthreads();
  if (threadIdx.x == 0) {
    int off = 0, b1 = 0, b2 = 0, q1 = 0;
    for (int g = 0; g < 4; ++g) {
      int c = cnt[g];
      hdr[g] = c;
      hdr[8 + g] = off;
      hdr[4 + g] = off;   // cursor
      hdr[13 + g] = b1;
      hdr[18 + g] = b2;
      hdr[23 + g] = q1;
      int mt = (c + 127) >> 7;   // 128-row m-tiles
      int mq = (c + 255) >> 8;   // 256-row m-tiles
      off += c;
      b1 += mt * 16;
      b2 += mt * 4;
      q1 += mq * 8;              // GEMM1: 8 n-tiles of 256
    }
    hdr[12] = off; hdr[17] = b1; hdr[22] = b2; hdr[27] = q1;
  }
}

// LDS-aggregated fill: one global atomic per (block, expert).
__global__ void k_fill(const int* __restrict__ b_seq, int* __restrict__ hdr,
                       int* __restrict__ perm) {
  __shared__ int lcnt[4], base[4];
  const int tid = threadIdx.x;
  if (tid < 4) lcnt[tid] = 0;
  __syncthreads();
  const int i = blockIdx.x * 256 + tid;
  const int g = b_seq[i];
  int r = -1;
  if (g > 0) r = atomicAdd(&lcnt[g - 1], 1);
  __syncthreads();
  if (tid < 4) {
    int c = lcnt[tid];
    base[tid] = c ? atomicAdd(&hdr[4 + tid], c) : 0;
  }
  __syncthreads();
  if (g > 0) perm[base[g - 1] + r] = i;
}

// Gather + convert x into packed A tiles: xa[mtile][ks(8)][128][64].
// One block per (mtile, ks). OOB rows zero-filled.
__global__ __launch_bounds__(256)
void k_pack_a(const float* __restrict__ x, const int* __restrict__ hdr,
              const int* __restrict__ perm, __hip_bfloat16* __restrict__ xa) {
  const int nmt = hdr[17] >> 4;
  const int b = blockIdx.x >> 3, ks = blockIdx.x & 7;
  if (b >= nmt) return;
  int g = 0;
  while ((hdr[13 + g + 1] >> 4) <= b) ++g;
  const int mt = b - (hdr[13 + g] >> 4);
  const int off = hdr[8 + g], cnt = hdr[g];
  int nrows = cnt - (mt << 7);
  nrows = nrows > 128 ? 128 : nrows;
  const int t = threadIdx.x, r = t >> 1, h = t & 1;
  __hip_bfloat16* dst =
      xa + ((size_t)b << 16) + (ks << 13) + r * 64 + h * 32;
  if (r < nrows) {
    const float* src = x + (size_t)perm[off + (mt << 7) + r] * HDIM +
                       (ks << 6) + (h << 5);
    union { __hip_bfloat16 b16[32]; s16x8 v[4]; } u;
#pragma unroll
    for (int p = 0; p < 8; ++p) {
      float4 vv = *(const float4*)(src + p * 4);
      u.b16[p * 4 + 0] = __float2bfloat16(vv.x);
      u.b16[p * 4 + 1] = __float2bfloat16(vv.y);
      u.b16[p * 4 + 2] = __float2bfloat16(vv.z);
      u.b16[p * 4 + 3] = __float2bfloat16(vv.w);
    }
    s16x8* d = (s16x8*)dst;
#pragma unroll
    for (int p = 0; p < 4; ++p) d[p] = u.v[p];
  } else {
    const s16x8 zz = {0, 0, 0, 0, 0, 0, 0, 0};
    s16x8* d = (s16x8*)dst;
#pragma unroll
    for (int p = 0; p < 4; ++p) d[p] = zz;
  }
}

// Transpose+convert W into PACKED K-step tiles:
//   dst tile = (g*(C/128) + (rI/128))*(R/64) + kI/64, elem [rI&127][kI&63]
__global__ void k_transpose_cvt(const float* __restrict__ src,
                                __hip_bfloat16* __restrict__ dst, int R, int C) {
  __shared__ float tile[64][69];   // pad 69: conflict-free col reads
  const int g = blockIdx.z;
  const float* S = src + (size_t)g * R * C;
  const int c0 = blockIdx.x << 6, r0 = blockIdx.y << 6;
  const int t = threadIdx.x;
  const int lr = t >> 4, lc = (t & 15) << 2;
#pragma unroll
  for (int p = 0; p < 4; ++p) {
    float4 v = *(const float4*)(S + (size_t)(r0 + lr + p * 16) * C + c0 + lc);
    float* tr = &tile[lr + p * 16][lc];
    tr[0] = v.x; tr[1] = v.y; tr[2] = v.z; tr[3] = v.w;
  }
  __syncthreads();
  const int c = t >> 2, rq = t & 3;
  union { __hip_bfloat16 b[8]; s16x8 v; } u0, u1;
#pragma unroll
  for (int j = 0; j < 8; ++j) {
    u0.b[j] = __float2bfloat16(tile[rq * 16 + j][c]);
    u1.b[j] = __float2bfloat16(tile[rq * 16 + 8 + j][c]);
  }
  const int rI = c0 + c, kI = r0 + rq * 16;
  const size_t idx =
      ((size_t)((g * (C >> 7) + (rI >> 7)) * (R >> 6) + (kI >> 6)) << 13) +
      ((rI & 127) << 6) + (kI & 63);
  *(s16x8*)(dst + idx) = u0.v;
  *(s16x8*)(dst + idx + 8) = u1.v;
}

__device__ __forceinline__ f32x4 mfma16(s16x8 a, s16x8 b, f32x4 c) {
  asm("v_mfma_f32_16x16x32_bf16 %0, %1, %2, %0" : "+v"(c) : "v"(a), "v"(b));
  return c;
}

__device__ __forceinline__ void gload16(const void* g, void* lds) {
  __builtin_amdgcn_global_load_lds(
      (const __attribute__((address_space(1))) unsigned int*)g,
      (__attribute__((address_space(3))) unsigned int*)lds, 16, 0, 0);
}

// GEMM1: 256x256 tile, BK=64, 1024 thr = 16 waves (4m x 4n, 64x64 each).
// A = 2 packed xa mtiles; B = 2 packed W1p tiles (layouts unchanged).
// Staging: 64 x 1KB contiguous units/step; waves 0-7 stage A (4 units each),
// waves 8-15 stage B. Same within-block XOR swizzle and fragment-read math
// as r15 (proven). T4: STAGE(s+1,p^1) -> vmcnt(4) -> barrier ->
// COMPUTE(p) -> barrier. Epilogue: relu+bias, 2 half-passes through LDS
// (stride 560, col-block XOR), 128B stores into Hp packed layout.
__global__ __launch_bounds__(1024, 4)
void k_gemm1(const int* __restrict__ hdr,
             const __hip_bfloat16* __restrict__ Ap,
             const __hip_bfloat16* __restrict__ Bp,
             const float* __restrict__ bias,
             __hip_bfloat16* __restrict__ Hout) {
  constexpr int NS = 8;                       // K-steps (512/64)
  const int* tb = hdr + 23;
  const int total = tb[4];

  __shared__ __align__(16) char LDS[131072];  // A dbuf 64KB | B dbuf 64KB

  const int idx = blockIdx.x;
  if (idx >= total) return;
  // m204 runtime-bijective XCD swizzle
  const int qc = total >> 3, rc = total & 7;
  const int xcd = idx & 7;
  const int cbase = (xcd < rc) ? xcd * (qc + 1) : rc * (qc + 1) + (xcd - rc) * qc;
  const int w = cbase + (idx >> 3);

  const int tid = threadIdx.x, lane = tid & 63, wv = tid >> 6;
  const int wr = wv >> 2, wcn = wv & 3;       // wave grid 4m x 4n
  const int l15 = lane & 15, lq = lane >> 4;
  const int rsub = lane >> 3, c8 = lane & 7;

  int g = 0;
  while (tb[g + 1] <= w) ++g;
  const int local = w - tb[g];
  const int mt = local >> 3, nt = local & 7;
  const int cnt = hdr[g];
  const int aB = hdr[13 + g] >> 4;            // xa 128-mtile base
  const int mtc = (hdr[13 + g + 1] >> 4) - aB;
  const int hB = hdr[18 + g] >> 2;            // Hp 128-mtile base
  const int pA0 = aB + (mt << 1);
  const int pA1 = aB + ((2 * mt + 1 < mtc) ? 2 * mt + 1 : mtc - 1);
  const int bt0 = g * 16 + (nt << 1);

  const int lelem = rsub * 64 + ((c8 ^ rsub) << 3);
  const bool isA = wv < 8;
  const int wvh = wv & 7;

  // per-instruction source bases and LDS dest offsets (unrolled -> regs)
  const __hip_bfloat16* srcb[4];
  int dstoff[4];
#pragma unroll
  for (int i = 0; i < 4; ++i) {
    const int u = (wvh << 2) + i;             // 0..31 within A or B
    const int rb = u >> 4, v = u & 15;
    const int tIdx = isA ? (rb ? pA1 : pA0) : (bt0 + rb);
    srcb[i] = (isA ? Ap : Bp) + (((size_t)tIdx * NS) << 13) + v * 512 + lelem;
    dstoff[i] = (isA ? 0 : 65536) + (rb << 14) + (v << 10);
  }

  f32x4 acc[4][4];
  const f32x4 fz = {0.f, 0.f, 0.f, 0.f};
#pragma unroll
  for (int m = 0; m < 4; ++m)
#pragma unroll
    for (int n = 0; n < 4; ++n) acc[m][n] = fz;

  auto STAGE = [&](int s, int p) {
    const size_t so = (size_t)s << 13;
#pragma unroll
    for (int i = 0; i < 4; ++i)
      gload16(srcb[i] + so, LDS + dstoff[i] + (p << 15));
  };
  auto COMPUTE = [&](int p) {
    const char* Ab = LDS + (p << 15);
    const char* Bb = LDS + 65536 + (p << 15);
#pragma unroll
    for (int kk = 0; kk < 2; ++kk) {
      const int kb = (kk << 6) + (lq << 4);
      s16x8 a[4], b[4];
#pragma unroll
      for (int m = 0; m < 4; ++m) {
        const int rg = (wr << 6) + (m << 4) + l15;
        a[m] = *(const s16x8*)(Ab + ((rg >> 7) << 14) + ((rg & 127) << 7) +
                               (kb ^ ((rg & 7) << 4)));
      }
#pragma unroll
      for (int n = 0; n < 4; ++n) {
        const int cg = (wcn << 6) + (n << 4) + l15;
        b[n] = *(const s16x8*)(Bb + ((cg >> 7) << 14) + ((cg & 127) << 7) +
                               (kb ^ ((cg & 7) << 4)));
      }
      __builtin_amdgcn_s_setprio(1);
#pragma unroll
      for (int m = 0; m < 4; ++m)
#pragma unroll
        for (int n = 0; n < 4; ++n)
          acc[m][n] = mfma16(a[m], b[n], acc[m][n]);
      __builtin_amdgcn_s_setprio(0);
    }
  };

  // T4 counted depth-2 pipeline
  STAGE(0, 0);
  for (int s = 0; s < NS; ++s) {
    const int p = s & 1;
    if (s + 1 < NS) {
      STAGE(s + 1, p ^ 1);
      asm volatile("s_waitcnt vmcnt(4)" ::: "memory");  // step-s retired
    } else {
      asm volatile("s_waitcnt vmcnt(0)" ::: "memory");
    }
    __builtin_amdgcn_s_barrier();
    asm volatile("" ::: "memory");
    COMPUTE(p);
    asm volatile("" ::: "memory");
    __builtin_amdgcn_s_barrier();
    asm volatile("" ::: "memory");
  }
  asm volatile("s_nop 7\ns_nop 7\ns_nop 7");  // MFMA->VALU hazard guard

  // epilogue: two 128-row half-passes through LDS
  const int rq = lq << 2;
#pragma unroll
  for (int h = 0; h < 2; ++h) {
    if ((wr >> 1) == h) {
#pragma unroll
      for (int n = 0; n < 4; ++n) {
        const int col = (wcn << 6) + (n << 4) + l15;
        const float bv = bias[g * FDIM + (nt << 8) + col];
#pragma unroll
        for (int m = 0; m < 4; ++m)
#pragma unroll
          for (int j = 0; j < 4; ++j) {
            const int r1 = ((wr & 1) << 6) + (m << 4) + rq + j;  // 0..127
            float v = acc[m][n][j] + bv;
            v = v > 0.f ? v : 0.f;
            *(__hip_bfloat16*)(LDS + r1 * 560 + ((wcn ^ (r1 & 3)) << 7) +
                               ((col & 63) << 1)) = __float2bfloat16(v);
          }
      }
    }
    __syncthreads();
    if (tid < 512) {
      const int r7 = tid >> 2, qb = tid & 3;
      if ((mt << 8) + (h << 7) + r7 < cnt) {
        const char* src = LDS + r7 * 560 + ((qb ^ (r7 & 3)) << 7);
        char* dst = (char*)(Hout +
            (((size_t)(hB + (mt << 1) + h) * 32 + (nt << 2) + qb) << 13) +
            r7 * 64);
#pragma unroll
        for (int q2 = 0; q2 < 8; ++q2)
          *(s16x8*)(dst + q2 * 16) = *(const s16x8*)(src + q2 * 16);
      }
    }
    __syncthreads();
  }
}

// GEMM2: r15-verbatim (128x128, BK=64, T4 depth-2, 256 thr).
// A = Hp packed (K=2048), B = W2p; +bias; fp32 scatter to d_out via perm.
__global__ __launch_bounds__(256, 2)
void k_gemm2(const int* __restrict__ hdr, const int* __restrict__ perm,
             const __hip_bfloat16* __restrict__ Ap,
             const __hip_bfloat16* __restrict__ Bp,
             const float* __restrict__ bias, float* __restrict__ Yout) {
  constexpr int NS = 32;
  constexpr int NT = 4;
  constexpr int NF = HDIM;
  const int* tb = hdr + 18;
  const int total = tb[4];

  __shared__ __align__(16) char LDS[65536];
  char* As = LDS;
  char* Bs = LDS + 32768;

  const int idx = blockIdx.x;
  if (idx >= total) return;
  const int qc = total >> 3, rc = total & 7;
  const int xcd = idx & 7;
  const int cbase = (xcd < rc) ? xcd * (qc + 1) : rc * (qc + 1) + (xcd - rc) * qc;
  const int w = cbase + (idx >> 3);

  const int tid = threadIdx.x, lane = tid & 63, wv = tid >> 6;
  const int wm = (wv >> 1) << 6, wn = (wv & 1) << 6;
  const int l15 = lane & 15, lq = lane >> 4;
  const int rsub = lane >> 3, c8 = lane & 7;

  int g = 0;
  while (tb[g + 1] <= w) ++g;
  const int local = w - tb[g];
  const int mt = local / NT, nt = local % NT;
  const int cnt = hdr[g], off = hdr[8 + g];
  int nrows = cnt - (mt << 7);
  nrows = nrows > 128 ? 128 : nrows;

  const int amt = (hdr[18 + g] >> 2) + mt;
  const int lelem = ((wv << 5) + rsub) * 64 + ((c8 ^ rsub) << 3);
  const __hip_bfloat16* abase = Ap + (((size_t)amt * NS) << 13) + lelem;
  const __hip_bfloat16* bbase =
      Bp + (((size_t)(g * NT + nt) * NS) << 13) + lelem;

  f32x4 acc[4][4];
  const f32x4 fz = {0.f, 0.f, 0.f, 0.f};
#pragma unroll
  for (int m = 0; m < 4; ++m)
#pragma unroll
    for (int n = 0; n < 4; ++n) acc[m][n] = fz;

  auto STAGE = [&](int s, int p) {
    const size_t so = (size_t)s << 13;
    char* Ad = As + (p << 14) + (wv << 12);
    char* Bd = Bs + (p << 14) + (wv << 12);
#pragma unroll
    for (int i = 0; i < 4; ++i) {
      gload16(abase + so + (i << 9), Ad + (i << 10));
      gload16(bbase + so + (i << 9), Bd + (i << 10));
    }
  };
  auto COMPUTE = [&](int p) {
    const char* Ab = As + (p << 14);
    const char* Bb = Bs + (p << 14);
#pragma unroll
    for (int kk = 0; kk < 2; ++kk) {
      const int kb = (kk << 6) + (lq << 4);
      s16x8 a[4], b[4];
#pragma unroll
      for (int m = 0; m < 4; ++m) {
        const int row = wm + (m << 4) + l15;
        a[m] = *(const s16x8*)(Ab + (row << 7) + (kb ^ ((row & 7) << 4)));
      }
#pragma unroll
      for (int n = 0; n < 4; ++n) {
        const int row = wn + (n << 4) + l15;
        b[n] = *(const s16x8*)(Bb + (row << 7) + (kb ^ ((row & 7) << 4)));
      }
      __builtin_amdgcn_s_setprio(1);
#pragma unroll
      for (int m = 0; m < 4; ++m)
#pragma unroll
        for (int n = 0; n < 4; ++n)
          acc[m][n] = mfma16(a[m], b[n], acc[m][n]);
      __builtin_amdgcn_s_setprio(0);
    }
  };

  STAGE(0, 0);
  for (int s = 0; s < NS; ++s) {
    const int p = s & 1;
    if (s + 1 < NS) {
      STAGE(s + 1, p ^ 1);
      asm volatile("s_waitcnt vmcnt(8)" ::: "memory");
    } else {
      asm volatile("s_waitcnt vmcnt(0)" ::: "memory");
    }
    __builtin_amdgcn_s_barrier();
    asm volatile("" ::: "memory");
    COMPUTE(p);
    asm volatile("" ::: "memory");
    __builtin_amdgcn_s_barrier();
    asm volatile("" ::: "memory");
  }
  asm volatile("s_nop 7\ns_nop 7\ns_nop 7");

  const int rq = lq << 2;
#pragma unroll
  for (int n = 0; n < 4; ++n) {
    const int ncol = (nt << 7) + wn + (n << 4) + l15;
    const float bv = bias[g * NF + ncol];
#pragma unroll
    for (int m = 0; m < 4; ++m)
#pragma unroll
      for (int j = 0; j < 4; ++j) {
        const int rl = wm + (m << 4) + rq + j;
        if (rl < nrows) {
          const int tok = perm[off + (mt << 7) + rl];
          Yout[((size_t)tok << 9) + ncol] = acc[m][n][j] + bv;
        }
      }
  }
}

extern "C" void kernel_launch(void* const* d_in, const int* in_sizes, int n_in,
                              void* d_out, int out_size, void* d_ws,
                              size_t ws_size, hipStream_t stream) {
  const float* x    = (const float*)d_in[0];
  const int* b_seq  = (const int*)d_in[1];
  const float* W1   = (const float*)d_in[2];
  const float* B1   = (const float*)d_in[3];
  const float* W2   = (const float*)d_in[4];
  const float* B2   = (const float*)d_in[5];
  float* out        = (float*)d_out;

  char* ws = (char*)d_ws;
  int* hdr  = (int*)ws;                          // 1 KB header
  int* perm = (int*)(ws + 1024);                 // 64 KB
  __hip_bfloat16* xa  = (__hip_bfloat16*)(ws + 66560);   // 132 mtiles
  __hip_bfloat16* W1p = xa + (size_t)MAXMT * 8 * 8192;   // [4*16][8] tiles
  __hip_bfloat16* W2p = W1p + (size_t)NEXP * FDIM * HDIM;// [4*4][32] tiles
  __hip_bfloat16* Hp  = W2p + (size_t)NEXP * HDIM * FDIM;// 132*32 tiles

  const int n4 = NTOK * HDIM / 4;

  k_init<<<2048, 256, 0, stream>>>(b_seq, (float4*)out, n4);
  k_count_scan<<<1, 1024, 0, stream>>>((const int4*)b_seq, hdr);
  k_fill<<<NTOK / 256, 256, 0, stream>>>(b_seq, hdr, perm);
  k_pack_a<<<MAXMT * 8, 256, 0, stream>>>(x, hdr, perm, xa);
  k_transpose_cvt<<<dim3(FDIM / 64, HDIM / 64, NEXP), 256, 0, stream>>>(
      W1, W1p, HDIM, FDIM);
  k_transpose_cvt<<<dim3(HDIM / 64, FDIM / 64, NEXP), 256, 0, stream>>>(
      W2, W2p, FDIM, HDIM);
  // worst-case tile counts: 68 mq-tiles * 8 = 544 (GEMM1); 528 (GEMM2)
  k_gemm1<<<544, 1024, 0, stream>>>(hdr, xa, W1p, B1, Hp);
  k_gemm2<<<528, 256, 0, stream>>>(hdr, perm, Hp, W2p, B2, out);
}

// Round 17
// 130.219 us; speedup vs baseline: 1.0824x; 1.0824x over previous
//
#include <hip/hip_runtime.h>
#include <hip/hip_bf16.h>

// ---------------------------------------------------------------------------
// BehaviorSpecificPFF: token-routed 4-expert FFN.
//   y[tok] = relu(x[tok] @ W1[g] + B1[g]) @ W2[g] + B2[g],  g = b_seq[tok]-1
//   b_seq==0 -> zeros.
// Round 17: GEMM1 LDS-FREE fragment-direct. xa and W1p are pre-packed in
// MFMA-fragment order ([ks][kk][rowblock][lane] 1KB blocks), so each operand
// fragment is ONE contiguous global_load_dwordx4 into MFMA input VGPRs.
// No staging LDS, no K-loop barriers, no swizzle; 4-set distance-2 register
// pipeline per wave; waves stream independently. Tests the hypothesis that
// the ~13 B/cy/CU wall (invariant across r3-r16) is the gload_lds+barrier
// path (m151: reg path = 39 B/cy; m233: stage+vmcnt+bar = 72% of 2-phase).
// GEMM2 r15-verbatim as control; Hp layout unchanged. count_scan merged
// into k_init.
// ---------------------------------------------------------------------------

typedef short s16x8 __attribute__((ext_vector_type(8)));
typedef float f32x4 __attribute__((ext_vector_type(4)));

#define NTOK   16384
#define HDIM   512
#define FDIM   2048
#define NEXP   4
#define MAXMT  132   // worst-case total 128-row m-tiles (4 experts)

// ---- header layout (ints) in ws ----
// [0..3] counts  [4..7] cursors  [8..12] token offsets ([12]=total)
// [13..17] gemm1 tile bases, mt-base = hdr[13+g]>>4 ([17]=total)
// [18..22] gemm2 tile bases, mt-base = hdr[18+g]>>2

__global__ void k_init(const int4* __restrict__ b4,
                       const int* __restrict__ b_seq,
                       float4* __restrict__ out, int n4,
                       int* __restrict__ hdr) {
  if (blockIdx.x == 0) {   // fused count+scan
    __shared__ int cnt[4];
    const int t = threadIdx.x;
    if (t < 4) cnt[t] = 0;
    __syncthreads();
    int c0 = 0, c1 = 0, c2 = 0, c3 = 0;
    for (int i = t; i < NTOK / 4; i += 256) {
      int4 v = b4[i];
      c0 += (v.x == 1) + (v.y == 1) + (v.z == 1) + (v.w == 1);
      c1 += (v.x == 2) + (v.y == 2) + (v.z == 2) + (v.w == 2);
      c2 += (v.x == 3) + (v.y == 3) + (v.z == 3) + (v.w == 3);
      c3 += (v.x == 4) + (v.y == 4) + (v.z == 4) + (v.w == 4);
    }
    if (c0) atomicAdd(&cnt[0], c0);
    if (c1) atomicAdd(&cnt[1], c1);
    if (c2) atomicAdd(&cnt[2], c2);
    if (c3) atomicAdd(&cnt[3], c3);
    __syncthreads();
    if (t == 0) {
      int off = 0, b1 = 0, b2 = 0;
      for (int g = 0; g < 4; ++g) {
        int c = cnt[g];
        hdr[g] = c;
        hdr[8 + g] = off;
        hdr[4 + g] = off;   // cursor
        hdr[13 + g] = b1;
        hdr[18 + g] = b2;
        int mt = (c + 127) >> 7;
        off += c;
        b1 += mt * 16;
        b2 += mt * 4;
      }
      hdr[12] = off; hdr[17] = b1; hdr[22] = b2;
    }
  }
  float4 z; z.x = z.y = z.z = z.w = 0.f;
  for (int i = blockIdx.x * blockDim.x + threadIdx.x; i < n4;
       i += gridDim.x * blockDim.x) {
    // non-pad out rows are fully rewritten by GEMM2 every call; only padding
    // rows need zeros (out float4-row token = i>>7).
    if (b_seq[i >> 7] == 0) out[i] = z;
  }
}

// LDS-aggregated fill: one global atomic per (block, expert).
__global__ void k_fill(const int* __restrict__ b_seq, int* __restrict__ hdr,
                       int* __restrict__ perm) {
  __shared__ int lcnt[4], base[4];
  const int tid = threadIdx.x;
  if (tid < 4) lcnt[tid] = 0;
  __syncthreads();
  const int i = blockIdx.x * 256 + tid;
  const int g = b_seq[i];
  int r = -1;
  if (g > 0) r = atomicAdd(&lcnt[g - 1], 1);
  __syncthreads();
  if (tid < 4) {
    int c = lcnt[tid];
    base[tid] = c ? atomicAdd(&hdr[4 + tid], c) : 0;
  }
  __syncthreads();
  if (g > 0) perm[base[g - 1] + r] = i;
}

// Gather + convert x into FRAGMENT-ORDER A tiles:
//   xa[mtile][ks][kk][rb][lane] where lane l holds row rb*16+(l&15),
//   k-elems ks*64 + kk*32 + (l>>4)*8 .. +7 (16B per lane-slot).
// One block per (mtile, ks); thread t covers 4 consecutive lane-slots of
// group (kk = t>>7, rb = (t>>4)&7), l = (t&15)*4 + i. OOB rows zero-filled.
__global__ __launch_bounds__(256)
void k_pack_a(const float* __restrict__ x, const int* __restrict__ hdr,
              const int* __restrict__ perm, __hip_bfloat16* __restrict__ xa) {
  const int nmt = hdr[17] >> 4;
  const int b = blockIdx.x >> 3, ks = blockIdx.x & 7;
  if (b >= nmt) return;
  int g = 0;
  while ((hdr[13 + g + 1] >> 4) <= b) ++g;
  const int mt = b - (hdr[13 + g] >> 4);
  const int off = hdr[8 + g], cnt = hdr[g];
  int nrows = cnt - (mt << 7);
  nrows = nrows > 128 ? 128 : nrows;
  const int t = threadIdx.x;
  const int kk = t >> 7, rb = (t >> 4) & 7, l0 = (t & 15) << 2;
  __hip_bfloat16* dst = xa + ((size_t)b << 16) + (ks << 13) +
                        ((((kk << 3) + rb) << 6) + l0) * 8;
#pragma unroll
  for (int i = 0; i < 4; ++i) {
    const int l = l0 + i;
    const int row = (rb << 4) + (l & 15);
    union { __hip_bfloat16 b16[8]; s16x8 v; } u;
    if (row < nrows) {
      const float* src = x + (size_t)perm[off + (mt << 7) + row] * HDIM +
                         (ks << 6) + (kk << 5) + ((l >> 4) << 3);
      float4 v0 = *(const float4*)(src);
      float4 v1 = *(const float4*)(src + 4);
      u.b16[0] = __float2bfloat16(v0.x); u.b16[1] = __float2bfloat16(v0.y);
      u.b16[2] = __float2bfloat16(v0.z); u.b16[3] = __float2bfloat16(v0.w);
      u.b16[4] = __float2bfloat16(v1.x); u.b16[5] = __float2bfloat16(v1.y);
      u.b16[6] = __float2bfloat16(v1.z); u.b16[7] = __float2bfloat16(v1.w);
    } else {
      const s16x8 zz = {0, 0, 0, 0, 0, 0, 0, 0};
      u.v = zz;
    }
    *(s16x8*)(dst + i * 8) = u.v;
  }
}

// Transpose+convert W into packed K-step tiles.
// FRAG=true  (W1p): fragment order [tile][ks][kk][rb][lane] (GEMM1 direct).
// FRAG=false (W2p): old order [tile][ks][row128][k64] (GEMM2 LDS path).
// grid (C/64, R/64, NEXP), block 256.
template <bool FRAG>
__global__ void k_transpose_cvt(const float* __restrict__ src,
                                __hip_bfloat16* __restrict__ dst, int R, int C) {
  __shared__ float tile[64][69];   // pad 69: conflict-free col reads
  const int g = blockIdx.z;
  const float* S = src + (size_t)g * R * C;
  const int c0 = blockIdx.x << 6, r0 = blockIdx.y << 6;
  const int t = threadIdx.x;
  const int lr = t >> 4, lc = (t & 15) << 2;
#pragma unroll
  for (int p = 0; p < 4; ++p) {
    float4 v = *(const float4*)(S + (size_t)(r0 + lr + p * 16) * C + c0 + lc);
    float* tr = &tile[lr + p * 16][lc];
    tr[0] = v.x; tr[1] = v.y; tr[2] = v.z; tr[3] = v.w;
  }
  __syncthreads();
  const int c = t >> 2, rq = t & 3;
  union { __hip_bfloat16 b[8]; s16x8 v; } u0, u1;
#pragma unroll
  for (int j = 0; j < 8; ++j) {
    u0.b[j] = __float2bfloat16(tile[rq * 16 + j][c]);
    u1.b[j] = __float2bfloat16(tile[rq * 16 + 8 + j][c]);
  }
  const int rI = c0 + c, kI = r0 + rq * 16;
  const int tl = g * (C >> 7) + (rI >> 7);
  if constexpr (!FRAG) {
    const size_t idx = (((size_t)tl * (R >> 6) + (kI >> 6)) << 13) +
                       ((rI & 127) << 6) + (kI & 63);
    *(s16x8*)(dst + idx) = u0.v;
    *(s16x8*)(dst + idx + 8) = u1.v;
  } else {
    const int ks = kI >> 6, kk = (kI >> 5) & 1, lq0 = (kI >> 3) & 3;
    const int rb = (rI & 127) >> 4;
    const size_t base = (((size_t)tl * (R >> 6) + ks) << 13) +
                        ((((kk << 3) + rb) << 6) + (lq0 << 4) + (rI & 15)) * 8;
    *(s16x8*)(dst + base) = u0.v;          // lane lq0*16 + l15
    *(s16x8*)(dst + base + 128) = u1.v;    // lane (lq0+1)*16 + l15
  }
}

__device__ __forceinline__ f32x4 mfma16(s16x8 a, s16x8 b, f32x4 c) {
  asm("v_mfma_f32_16x16x32_bf16 %0, %1, %2, %0" : "+v"(c) : "v"(a), "v"(b));
  return c;
}

__device__ __forceinline__ void gload16(const void* g, void* lds) {
  __builtin_amdgcn_global_load_lds(
      (const __attribute__((address_space(1))) unsigned int*)g,
      (__attribute__((address_space(3))) unsigned int*)lds, 16, 0, 0);
}

// GEMM1 (LDS-free): 128x128 tile, BK=64, 4 waves (2m x 2n, 64x64 each).
// Operands in fragment order: each fragment = 1 contiguous 1KB load
// (lane*16B) straight into MFMA input VGPRs. No barriers, no staging LDS.
// 4 named register sets, distance-2 pipeline: at phase p (use set p%4),
// loads for p+2 are in flight; compiler inserts counted waitcnts.
// LDS used only for the C-stage epilogue (relu+bias -> Hp packed layout).
__global__ __launch_bounds__(256)
void k_gemm1(const int* __restrict__ hdr,
             const __hip_bfloat16* __restrict__ Ap,
             const __hip_bfloat16* __restrict__ Bp,
             const float* __restrict__ bias,
             __hip_bfloat16* __restrict__ Hout) {
  constexpr int NS = 8, NT = 16;
  const int* tb = hdr + 13;
  const int total = tb[4];

  __shared__ __align__(16) char LDS[34816];   // C-stage only (128 x 272B)

  const int idx = blockIdx.x;
  if (idx >= total) return;
  // m204 runtime-bijective XCD swizzle
  const int qc = total >> 3, rc = total & 7;
  const int xcd = idx & 7;
  const int cbase = (xcd < rc) ? xcd * (qc + 1) : rc * (qc + 1) + (xcd - rc) * qc;
  const int w = cbase + (idx >> 3);

  const int tid = threadIdx.x, lane = tid & 63, wv = tid >> 6;
  const int wm = (wv >> 1) << 6, wn = (wv & 1) << 6;
  const int l15 = lane & 15, lq = lane >> 4;

  int g = 0;
  while (tb[g + 1] <= w) ++g;
  const int local = w - tb[g];
  const int mt = local / NT, nt = local % NT;
  const int cnt = hdr[g];
  int nrows = cnt - (mt << 7);
  nrows = nrows > 128 ? 128 : nrows;

  const int amt = (hdr[13 + g] >> 4) + mt;
  // per-wave fragment bases: + wave row/col-block*512 + lane*8 elems
  const __hip_bfloat16* aF = Ap + (((size_t)amt * NS) << 13) +
                             (((wv >> 1) << 2) << 9) + lane * 8;
  const __hip_bfloat16* bF = Bp + (((size_t)(g * NT + nt) * NS) << 13) +
                             (((wv & 1) << 2) << 9) + lane * 8;

  f32x4 acc[4][4];
  const f32x4 fz = {0.f, 0.f, 0.f, 0.f};
#pragma unroll
  for (int m = 0; m < 4; ++m)
#pragma unroll
    for (int n = 0; n < 4; ++n) acc[m][n] = fz;

  s16x8 a0[4], b0[4], a1[4], b1[4], a2[4], b2[4], a3[4], b3[4];
  auto LD = [&](int ph, s16x8* a, s16x8* b) {
    const size_t o = (size_t)ph << 12;          // ph*8 frag-blocks*512 elems
#pragma unroll
    for (int i = 0; i < 4; ++i) {
      a[i] = *(const s16x8*)(aF + o + (i << 9));
      b[i] = *(const s16x8*)(bF + o + (i << 9));
    }
  };
  auto MM = [&](s16x8* a, s16x8* b) {
#pragma unroll
    for (int m = 0; m < 4; ++m)
#pragma unroll
      for (int n = 0; n < 4; ++n)
        acc[m][n] = mfma16(a[m], b[n], acc[m][n]);
  };

  LD(0, a0, b0);
  LD(1, a1, b1);
#pragma unroll
  for (int ph = 0; ph < 2 * NS; ph += 4) {      // 16 phases (s,kk)
    if (ph + 2 < 2 * NS) LD(ph + 2, a2, b2);
    MM(a0, b0);
    if (ph + 3 < 2 * NS) LD(ph + 3, a3, b3);
    MM(a1, b1);
    if (ph + 4 < 2 * NS) LD(ph + 4, a0, b0);
    MM(a2, b2);
    if (ph + 5 < 2 * NS) LD(ph + 5, a1, b1);
    MM(a3, b3);
  }
  asm volatile("s_nop 7\ns_nop 7\ns_nop 7");    // MFMA->VALU hazard guard

  // epilogue (r15-proven): relu+bias via LDS C-stage (stride 272), then
  // 128B stores into Hp's packed layout (GEMM2-compatible).
  const int rq = lq << 2;
#pragma unroll
  for (int n = 0; n < 4; ++n) {
    const int col = wn + (n << 4) + l15;
    const float bv = bias[g * FDIM + (nt << 7) + col];
#pragma unroll
    for (int m = 0; m < 4; ++m)
#pragma unroll
      for (int j = 0; j < 4; ++j) {
        const int row = wm + (m << 4) + rq + j;
        float v = acc[m][n][j] + bv;
        v = v > 0.f ? v : 0.f;
        *(__hip_bfloat16*)(LDS + row * 272 + col * 2) = __float2bfloat16(v);
      }
  }
  __syncthreads();
  const int r = tid >> 1, hf = tid & 1;
  if (r < nrows) {
    const char* src = LDS + r * 272 + hf * 128;
    const size_t tIdx =
        ((size_t)((hdr[18 + g] >> 2) + mt) * 32 + (nt << 1) + hf);
    char* dst = (char*)(Hout + (tIdx << 13) + r * 64);
#pragma unroll
    for (int q = 0; q < 8; ++q)
      *(s16x8*)(dst + q * 16) = *(const s16x8*)(src + q * 16);
  }
}

// GEMM2: r15-verbatim (128x128, BK=64, T4 depth-2 counted pipeline).
// A = Hp packed (K=2048), B = W2p; +bias; fp32 scatter to d_out via perm.
__global__ __launch_bounds__(256, 2)
void k_gemm2(const int* __restrict__ hdr, const int* __restrict__ perm,
             const __hip_bfloat16* __restrict__ Ap,
             const __hip_bfloat16* __restrict__ Bp,
             const float* __restrict__ bias, float* __restrict__ Yout) {
  constexpr int NS = 32;
  constexpr int NT = 4;
  constexpr int NF = HDIM;
  const int* tb = hdr + 18;
  const int total = tb[4];

  __shared__ __align__(16) char LDS[65536];
  char* As = LDS;
  char* Bs = LDS + 32768;

  const int idx = blockIdx.x;
  if (idx >= total) return;
  const int qc = total >> 3, rc = total & 7;
  const int xcd = idx & 7;
  const int cbase = (xcd < rc) ? xcd * (qc + 1) : rc * (qc + 1) + (xcd - rc) * qc;
  const int w = cbase + (idx >> 3);

  const int tid = threadIdx.x, lane = tid & 63, wv = tid >> 6;
  const int wm = (wv >> 1) << 6, wn = (wv & 1) << 6;
  const int l15 = lane & 15, lq = lane >> 4;
  const int rsub = lane >> 3, c8 = lane & 7;

  int g = 0;
  while (tb[g + 1] <= w) ++g;
  const int local = w - tb[g];
  const int mt = local / NT, nt = local % NT;
  const int cnt = hdr[g], off = hdr[8 + g];
  int nrows = cnt - (mt << 7);
  nrows = nrows > 128 ? 128 : nrows;

  const int amt = (hdr[18 + g] >> 2) + mt;
  const int lelem = ((wv << 5) + rsub) * 64 + ((c8 ^ rsub) << 3);
  const __hip_bfloat16* abase = Ap + (((size_t)amt * NS) << 13) + lelem;
  const __hip_bfloat16* bbase =
      Bp + (((size_t)(g * NT + nt) * NS) << 13) + lelem;

  f32x4 acc[4][4];
  const f32x4 fz = {0.f, 0.f, 0.f, 0.f};
#pragma unroll
  for (int m = 0; m < 4; ++m)
#pragma unroll
    for (int n = 0; n < 4; ++n) acc[m][n] = fz;

  auto STAGE = [&](int s, int p) {
    const size_t so = (size_t)s << 13;
    char* Ad = As + (p << 14) + (wv << 12);
    char* Bd = Bs + (p << 14) + (wv << 12);
#pragma unroll
    for (int i = 0; i < 4; ++i) {
      gload16(abase + so + (i << 9), Ad + (i << 10));
      gload16(bbase + so + (i << 9), Bd + (i << 10));
    }
  };
  auto COMPUTE = [&](int p) {
    const char* Ab = As + (p << 14);
    const char* Bb = Bs + (p << 14);
#pragma unroll
    for (int kk = 0; kk < 2; ++kk) {
      const int kb = (kk << 6) + (lq << 4);
      s16x8 a[4], b[4];
#pragma unroll
      for (int m = 0; m < 4; ++m) {
        const int row = wm + (m << 4) + l15;
        a[m] = *(const s16x8*)(Ab + (row << 7) + (kb ^ ((row & 7) << 4)));
      }
#pragma unroll
      for (int n = 0; n < 4; ++n) {
        const int row = wn + (n << 4) + l15;
        b[n] = *(const s16x8*)(Bb + (row << 7) + (kb ^ ((row & 7) << 4)));
      }
      __builtin_amdgcn_s_setprio(1);
#pragma unroll
      for (int m = 0; m < 4; ++m)
#pragma unroll
        for (int n = 0; n < 4; ++n)
          acc[m][n] = mfma16(a[m], b[n], acc[m][n]);
      __builtin_amdgcn_s_setprio(0);
    }
  };

  STAGE(0, 0);
  for (int s = 0; s < NS; ++s) {
    const int p = s & 1;
    if (s + 1 < NS) {
      STAGE(s + 1, p ^ 1);
      asm volatile("s_waitcnt vmcnt(8)" ::: "memory");
    } else {
      asm volatile("s_waitcnt vmcnt(0)" ::: "memory");
    }
    __builtin_amdgcn_s_barrier();
    asm volatile("" ::: "memory");
    COMPUTE(p);
    asm volatile("" ::: "memory");
    __builtin_amdgcn_s_barrier();
    asm volatile("" ::: "memory");
  }
  asm volatile("s_nop 7\ns_nop 7\ns_nop 7");

  const int rq = lq << 2;
#pragma unroll
  for (int n = 0; n < 4; ++n) {
    const int ncol = (nt << 7) + wn + (n << 4) + l15;
    const float bv = bias[g * NF + ncol];
#pragma unroll
    for (int m = 0; m < 4; ++m)
#pragma unroll
      for (int j = 0; j < 4; ++j) {
        const int rl = wm + (m << 4) + rq + j;
        if (rl < nrows) {
          const int tok = perm[off + (mt << 7) + rl];
          Yout[((size_t)tok << 9) + ncol] = acc[m][n][j] + bv;
        }
      }
  }
}

extern "C" void kernel_launch(void* const* d_in, const int* in_sizes, int n_in,
                              void* d_out, int out_size, void* d_ws,
                              size_t ws_size, hipStream_t stream) {
  const float* x    = (const float*)d_in[0];
  const int* b_seq  = (const int*)d_in[1];
  const float* W1   = (const float*)d_in[2];
  const float* B1   = (const float*)d_in[3];
  const float* W2   = (const float*)d_in[4];
  const float* B2   = (const float*)d_in[5];
  float* out        = (float*)d_out;

  char* ws = (char*)d_ws;
  int* hdr  = (int*)ws;                          // 1 KB header
  int* perm = (int*)(ws + 1024);                 // 64 KB
  __hip_bfloat16* xa  = (__hip_bfloat16*)(ws + 66560);   // 132 mtiles (frag)
  __hip_bfloat16* W1p = xa + (size_t)MAXMT * 8 * 8192;   // frag order
  __hip_bfloat16* W2p = W1p + (size_t)NEXP * FDIM * HDIM;// old packed order
  __hip_bfloat16* Hp  = W2p + (size_t)NEXP * HDIM * FDIM;// old packed order

  const int n4 = NTOK * HDIM / 4;

  k_init<<<2048, 256, 0, stream>>>((const int4*)b_seq, b_seq, (float4*)out,
                                   n4, hdr);
  k_fill<<<NTOK / 256, 256, 0, stream>>>(b_seq, hdr, perm);
  k_pack_a<<<MAXMT * 8, 256, 0, stream>>>(x, hdr, perm, xa);
  k_transpose_cvt<true><<<dim3(FDIM / 64, HDIM / 64, NEXP), 256, 0, stream>>>(
      W1, W1p, HDIM, FDIM);
  k_transpose_cvt<false><<<dim3(HDIM / 64, FDIM / 64, NEXP), 256, 0, stream>>>(
      W2, W2p, FDIM, HDIM);
  // grids cover worst-case tile counts; blocks past the actual total exit
  k_gemm1<<<2112, 256, 0, stream>>>(hdr, xa, W1p, B1, Hp);
  k_gemm2<<<528, 256, 0, stream>>>(hdr, perm, Hp, W2p, B2, out);
}

// Round 18
// 125.297 us; speedup vs baseline: 1.1249x; 1.0393x over previous
//
#include <hip/hip_runtime.h>
#include <hip/hip_bf16.h>

// ---------------------------------------------------------------------------
// BehaviorSpecificPFF: token-routed 4-expert FFN.
//   y[tok] = relu(x[tok] @ W1[g] + B1[g]) @ W2[g] + B2[g],  g = b_seq[tok]-1
//   b_seq==0 -> zeros.
// Round 18: PINNED distance-3 register pipeline on BOTH GEMMs (frag-direct,
// LDS-free K-loop). r17's VGPR=68 proved the compiler folded the 4-set
// pipeline (needs >=128 VGPR); sched_barrier(0) fences pin LD(ph+3) before
// MM(ph). GEMM2 ported to the same structure: Hp now written in fragment
// order by GEMM1's epilogue; W2p packed frag-order; GEMM2 has NO LDS.
// ---------------------------------------------------------------------------

typedef short s16x8 __attribute__((ext_vector_type(8)));
typedef float f32x4 __attribute__((ext_vector_type(4)));

#define NTOK   16384
#define HDIM   512
#define FDIM   2048
#define NEXP   4
#define MAXMT  132   // worst-case total 128-row m-tiles (4 experts)
#define SB()   __builtin_amdgcn_sched_barrier(0)

// ---- header layout (ints) in ws ----
// [0..3] counts  [4..7] cursors  [8..12] token offsets ([12]=total)
// [13..17] gemm1 tile bases, mt-base = hdr[13+g]>>4 ([17]=total)
// [18..22] gemm2 tile bases, mt-base = hdr[18+g]>>2

__global__ void k_init(const int4* __restrict__ b4,
                       const int* __restrict__ b_seq,
                       float4* __restrict__ out, int n4,
                       int* __restrict__ hdr) {
  if (blockIdx.x == 0) {   // fused count+scan
    __shared__ int cnt[4];
    const int t = threadIdx.x;
    if (t < 4) cnt[t] = 0;
    __syncthreads();
    int c0 = 0, c1 = 0, c2 = 0, c3 = 0;
    for (int i = t; i < NTOK / 4; i += 256) {
      int4 v = b4[i];
      c0 += (v.x == 1) + (v.y == 1) + (v.z == 1) + (v.w == 1);
      c1 += (v.x == 2) + (v.y == 2) + (v.z == 2) + (v.w == 2);
      c2 += (v.x == 3) + (v.y == 3) + (v.z == 3) + (v.w == 3);
      c3 += (v.x == 4) + (v.y == 4) + (v.z == 4) + (v.w == 4);
    }
    if (c0) atomicAdd(&cnt[0], c0);
    if (c1) atomicAdd(&cnt[1], c1);
    if (c2) atomicAdd(&cnt[2], c2);
    if (c3) atomicAdd(&cnt[3], c3);
    __syncthreads();
    if (t == 0) {
      int off = 0, b1 = 0, b2 = 0;
      for (int g = 0; g < 4; ++g) {
        int c = cnt[g];
        hdr[g] = c;
        hdr[8 + g] = off;
        hdr[4 + g] = off;   // cursor
        hdr[13 + g] = b1;
        hdr[18 + g] = b2;
        int mt = (c + 127) >> 7;
        off += c;
        b1 += mt * 16;
        b2 += mt * 4;
      }
      hdr[12] = off; hdr[17] = b1; hdr[22] = b2;
    }
  }
  float4 z; z.x = z.y = z.z = z.w = 0.f;
  for (int i = blockIdx.x * blockDim.x + threadIdx.x; i < n4;
       i += gridDim.x * blockDim.x) {
    // non-pad out rows are fully rewritten by GEMM2 every call; only padding
    // rows need zeros (out float4-row token = i>>7).
    if (b_seq[i >> 7] == 0) out[i] = z;
  }
}

// LDS-aggregated fill: one global atomic per (block, expert).
__global__ void k_fill(const int* __restrict__ b_seq, int* __restrict__ hdr,
                       int* __restrict__ perm) {
  __shared__ int lcnt[4], base[4];
  const int tid = threadIdx.x;
  if (tid < 4) lcnt[tid] = 0;
  __syncthreads();
  const int i = blockIdx.x * 256 + tid;
  const int g = b_seq[i];
  int r = -1;
  if (g > 0) r = atomicAdd(&lcnt[g - 1], 1);
  __syncthreads();
  if (tid < 4) {
    int c = lcnt[tid];
    base[tid] = c ? atomicAdd(&hdr[4 + tid], c) : 0;
  }
  __syncthreads();
  if (g > 0) perm[base[g - 1] + r] = i;
}

// Gather + convert x into FRAGMENT-ORDER A tiles:
//   xa[mtile][ks][kk][rb][lane]: lane l holds row rb*16+(l&15),
//   k = ks*64 + kk*32 + (l>>4)*8 .. +7 (16B per lane-slot).
// One block per (mtile, ks). OOB rows zero-filled.
__global__ __launch_bounds__(256)
void k_pack_a(const float* __restrict__ x, const int* __restrict__ hdr,
              const int* __restrict__ perm, __hip_bfloat16* __restrict__ xa) {
  const int nmt = hdr[17] >> 4;
  const int b = blockIdx.x >> 3, ks = blockIdx.x & 7;
  if (b >= nmt) return;
  int g = 0;
  while ((hdr[13 + g + 1] >> 4) <= b) ++g;
  const int mt = b - (hdr[13 + g] >> 4);
  const int off = hdr[8 + g], cnt = hdr[g];
  int nrows = cnt - (mt << 7);
  nrows = nrows > 128 ? 128 : nrows;
  const int t = threadIdx.x;
  const int kk = t >> 7, rb = (t >> 4) & 7, l0 = (t & 15) << 2;
  __hip_bfloat16* dst = xa + ((size_t)b << 16) + (ks << 13) +
                        ((((kk << 3) + rb) << 6) + l0) * 8;
#pragma unroll
  for (int i = 0; i < 4; ++i) {
    const int l = l0 + i;
    const int row = (rb << 4) + (l & 15);
    union { __hip_bfloat16 b16[8]; s16x8 v; } u;
    if (row < nrows) {
      const float* src = x + (size_t)perm[off + (mt << 7) + row] * HDIM +
                         (ks << 6) + (kk << 5) + ((l >> 4) << 3);
      float4 v0 = *(const float4*)(src);
      float4 v1 = *(const float4*)(src + 4);
      u.b16[0] = __float2bfloat16(v0.x); u.b16[1] = __float2bfloat16(v0.y);
      u.b16[2] = __float2bfloat16(v0.z); u.b16[3] = __float2bfloat16(v0.w);
      u.b16[4] = __float2bfloat16(v1.x); u.b16[5] = __float2bfloat16(v1.y);
      u.b16[6] = __float2bfloat16(v1.z); u.b16[7] = __float2bfloat16(v1.w);
    } else {
      const s16x8 zz = {0, 0, 0, 0, 0, 0, 0, 0};
      u.v = zz;
    }
    *(s16x8*)(dst + i * 8) = u.v;
  }
}

// Transpose+convert W into fragment-order packed K-step tiles:
//   tile tl = g*(C/128) + rI/128, kstep = kI/64; within the 8192-elem block
//   lane-slot ((kk*8+rb)*64 + lq*16 + (rI&15))*8 + e.
// grid (C/64, R/64, NEXP), block 256.
__global__ void k_transpose_cvt(const float* __restrict__ src,
                                __hip_bfloat16* __restrict__ dst, int R, int C) {
  __shared__ float tile[64][69];   // pad 69: conflict-free col reads
  const int g = blockIdx.z;
  const float* S = src + (size_t)g * R * C;
  const int c0 = blockIdx.x << 6, r0 = blockIdx.y << 6;
  const int t = threadIdx.x;
  const int lr = t >> 4, lc = (t & 15) << 2;
#pragma unroll
  for (int p = 0; p < 4; ++p) {
    float4 v = *(const float4*)(S + (size_t)(r0 + lr + p * 16) * C + c0 + lc);
    float* tr = &tile[lr + p * 16][lc];
    tr[0] = v.x; tr[1] = v.y; tr[2] = v.z; tr[3] = v.w;
  }
  __syncthreads();
  const int c = t >> 2, rq = t & 3;
  union { __hip_bfloat16 b[8]; s16x8 v; } u0, u1;
#pragma unroll
  for (int j = 0; j < 8; ++j) {
    u0.b[j] = __float2bfloat16(tile[rq * 16 + j][c]);
    u1.b[j] = __float2bfloat16(tile[rq * 16 + 8 + j][c]);
  }
  const int rI = c0 + c, kI = r0 + rq * 16;
  const int tl = g * (C >> 7) + (rI >> 7);
  const int ks = kI >> 6, kk = (kI >> 5) & 1, lq0 = (kI >> 3) & 3;
  const int rb = (rI & 127) >> 4;
  const size_t base = (((size_t)tl * (R >> 6) + ks) << 13) +
                      ((((kk << 3) + rb) << 6) + (lq0 << 4) + (rI & 15)) * 8;
  *(s16x8*)(dst + base) = u0.v;          // lane lq0*16 + l15
  *(s16x8*)(dst + base + 128) = u1.v;    // lane (lq0+1)*16 + l15
}

__device__ __forceinline__ f32x4 mfma16(s16x8 a, s16x8 b, f32x4 c) {
  asm("v_mfma_f32_16x16x32_bf16 %0, %1, %2, %0" : "+v"(c) : "v"(a), "v"(b));
  return c;
}

// GEMM1 (LDS-free K-loop, pinned pipeline): 128x128 tile, BK=64, 4 waves
// (2m x 2n). Fragment-order operands; each fragment = 1 contiguous 1KB load.
// Distance-3 pipeline with 4 named sets, sched_barrier(0)-pinned:
//   LD(0..2); loop { LD(ph+3); SB; MM(ph); SB; }.
// LDS only for the C-stage epilogue (relu+bias -> Hp FRAGMENT order).
__global__ __launch_bounds__(256)
void k_gemm1(const int* __restrict__ hdr,
             const __hip_bfloat16* __restrict__ Ap,
             const __hip_bfloat16* __restrict__ Bp,
             const float* __restrict__ bias,
             __hip_bfloat16* __restrict__ Hout) {
  constexpr int NS = 8, NT = 16, NPH = 2 * NS;
  const int* tb = hdr + 13;
  const int total = tb[4];

  __shared__ __align__(16) char LDS[34816];   // C-stage only (128 x 272B)

  const int idx = blockIdx.x;
  if (idx >= total) return;
  const int qc = total >> 3, rc = total & 7;
  const int xcd = idx & 7;
  const int cbase = (xcd < rc) ? xcd * (qc + 1) : rc * (qc + 1) + (xcd - rc) * qc;
  const int w = cbase + (idx >> 3);

  const int tid = threadIdx.x, lane = tid & 63, wv = tid >> 6;
  const int wm = (wv >> 1) << 6, wn = (wv & 1) << 6;
  const int l15 = lane & 15, lq = lane >> 4;

  int g = 0;
  while (tb[g + 1] <= w) ++g;
  const int local = w - tb[g];
  const int mt = local / NT, nt = local % NT;
  const int cnt = hdr[g];
  int nrows = cnt - (mt << 7);
  nrows = nrows > 128 ? 128 : nrows;

  const int amt = (hdr[13 + g] >> 4) + mt;
  const __hip_bfloat16* aF = Ap + (((size_t)amt * NS) << 13) +
                             (((wv >> 1) << 2) << 9) + lane * 8;
  const __hip_bfloat16* bF = Bp + (((size_t)(g * NT + nt) * NS) << 13) +
                             (((wv & 1) << 2) << 9) + lane * 8;

  f32x4 acc[4][4];
  const f32x4 fz = {0.f, 0.f, 0.f, 0.f};
#pragma unroll
  for (int m = 0; m < 4; ++m)
#pragma unroll
    for (int n = 0; n < 4; ++n) acc[m][n] = fz;

  s16x8 a0[4], b0[4], a1[4], b1[4], a2[4], b2[4], a3[4], b3[4];
  auto LD = [&](int ph, s16x8* a, s16x8* b) {
    const size_t o = (size_t)ph << 12;
#pragma unroll
    for (int i = 0; i < 4; ++i) {
      a[i] = *(const s16x8*)(aF + o + (i << 9));
      b[i] = *(const s16x8*)(bF + o + (i << 9));
    }
  };
  auto MM = [&](s16x8* a, s16x8* b) {
    __builtin_amdgcn_s_setprio(1);
#pragma unroll
    for (int m = 0; m < 4; ++m)
#pragma unroll
      for (int n = 0; n < 4; ++n)
        acc[m][n] = mfma16(a[m], b[n], acc[m][n]);
    __builtin_amdgcn_s_setprio(0);
  };

  LD(0, a0, b0); SB();
  LD(1, a1, b1); SB();
  LD(2, a2, b2); SB();
#pragma unroll
  for (int ph = 0; ph < NPH; ph += 4) {
    if (ph + 3 < NPH) LD(ph + 3, a3, b3);
    SB(); MM(a0, b0); SB();
    if (ph + 4 < NPH) LD(ph + 4, a0, b0);
    SB(); MM(a1, b1); SB();
    if (ph + 5 < NPH) LD(ph + 5, a1, b1);
    SB(); MM(a2, b2); SB();
    if (ph + 6 < NPH) LD(ph + 6, a2, b2);
    SB(); MM(a3, b3); SB();
  }
  asm volatile("s_nop 7\ns_nop 7\ns_nop 7");    // MFMA->VALU hazard guard

  // epilogue: relu+bias via LDS C-stage (stride 272), then 16B stores into
  // Hp in FRAGMENT order (GEMM2-direct-consumable).
  const int rq = lq << 2;
#pragma unroll
  for (int n = 0; n < 4; ++n) {
    const int col = wn + (n << 4) + l15;
    const float bv = bias[g * FDIM + (nt << 7) + col];
#pragma unroll
    for (int m = 0; m < 4; ++m)
#pragma unroll
      for (int j = 0; j < 4; ++j) {
        const int row = wm + (m << 4) + rq + j;
        float v = acc[m][n][j] + bv;
        v = v > 0.f ? v : 0.f;
        *(__hip_bfloat16*)(LDS + row * 272 + col * 2) = __float2bfloat16(v);
      }
  }
  __syncthreads();
  const int r = tid >> 1, hf = tid & 1;
  if (r < nrows) {
    const char* src = LDS + r * 272 + hf * 128;   // 64 bf16 for kstep 2nt+hf
    const int hmt = (hdr[18 + g] >> 2) + mt;
    __hip_bfloat16* dblk =
        Hout + (((size_t)hmt * 32 + (nt << 1) + hf) << 13);
    const int rb = r >> 4, l15r = r & 15;
#pragma unroll
    for (int kk2 = 0; kk2 < 2; ++kk2)
#pragma unroll
      for (int lq2 = 0; lq2 < 4; ++lq2) {
        s16x8 v = *(const s16x8*)(src + kk2 * 64 + lq2 * 16);
        *(s16x8*)(dblk +
                  ((((kk2 << 3) + rb) << 6) + (lq2 << 4) + l15r) * 8) = v;
      }
  }
}

// GEMM2 (LDS-free, pinned pipeline): 128x128 tile, BK=64, 4 waves (2m x 2n).
// A = Hp fragment order (K=2048, 32 ksteps); B = W2p fragment order.
// Same distance-3 pinned structure; no LDS; fp32 scatter epilogue via perm.
__global__ __launch_bounds__(256)
void k_gemm2(const int* __restrict__ hdr, const int* __restrict__ perm,
             const __hip_bfloat16* __restrict__ Ap,
             const __hip_bfloat16* __restrict__ Bp,
             const float* __restrict__ bias, float* __restrict__ Yout) {
  constexpr int NS = 32, NT = 4, NPH = 2 * NS;
  const int* tb = hdr + 18;
  const int total = tb[4];

  const int idx = blockIdx.x;
  if (idx >= total) return;
  const int qc = total >> 3, rc = total & 7;
  const int xcd = idx & 7;
  const int cbase = (xcd < rc) ? xcd * (qc + 1) : rc * (qc + 1) + (xcd - rc) * qc;
  const int w = cbase + (idx >> 3);

  const int tid = threadIdx.x, lane = tid & 63, wv = tid >> 6;
  const int wm = (wv >> 1) << 6, wn = (wv & 1) << 6;
  const int l15 = lane & 15, lq = lane >> 4;

  int g = 0;
  while (tb[g + 1] <= w) ++g;
  const int local = w - tb[g];
  const int mt = local / NT, nt = local % NT;
  const int cnt = hdr[g], off = hdr[8 + g];
  int nrows = cnt - (mt << 7);
  nrows = nrows > 128 ? 128 : nrows;

  const int amt = (hdr[18 + g] >> 2) + mt;
  const __hip_bfloat16* aF = Ap + (((size_t)amt * NS) << 13) +
                             (((wv >> 1) << 2) << 9) + lane * 8;
  const __hip_bfloat16* bF = Bp + (((size_t)(g * NT + nt) * NS) << 13) +
                             (((wv & 1) << 2) << 9) + lane * 8;

  f32x4 acc[4][4];
  const f32x4 fz = {0.f, 0.f, 0.f, 0.f};
#pragma unroll
  for (int m = 0; m < 4; ++m)
#pragma unroll
    for (int n = 0; n < 4; ++n) acc[m][n] = fz;

  s16x8 a0[4], b0[4], a1[4], b1[4], a2[4], b2[4], a3[4], b3[4];
  auto LD = [&](int ph, s16x8* a, s16x8* b) {
    const size_t o = (size_t)ph << 12;
#pragma unroll
    for (int i = 0; i < 4; ++i) {
      a[i] = *(const s16x8*)(aF + o + (i << 9));
      b[i] = *(const s16x8*)(bF + o + (i << 9));
    }
  };
  auto MM = [&](s16x8* a, s16x8* b) {
    __builtin_amdgcn_s_setprio(1);
#pragma unroll
    for (int m = 0; m < 4; ++m)
#pragma unroll
      for (int n = 0; n < 4; ++n)
        acc[m][n] = mfma16(a[m], b[n], acc[m][n]);
    __builtin_amdgcn_s_setprio(0);
  };

  LD(0, a0, b0); SB();
  LD(1, a1, b1); SB();
  LD(2, a2, b2); SB();
#pragma unroll
  for (int ph = 0; ph < NPH; ph += 4) {
    if (ph + 3 < NPH) LD(ph + 3, a3, b3);
    SB(); MM(a0, b0); SB();
    if (ph + 4 < NPH) LD(ph + 4, a0, b0);
    SB(); MM(a1, b1); SB();
    if (ph + 5 < NPH) LD(ph + 5, a1, b1);
    SB(); MM(a2, b2); SB();
    if (ph + 6 < NPH) LD(ph + 6, a2, b2);
    SB(); MM(a3, b3); SB();
  }
  asm volatile("s_nop 7\ns_nop 7\ns_nop 7");

  const int rq = lq << 2;
#pragma unroll
  for (int n = 0; n < 4; ++n) {
    const int ncol = (nt << 7) + wn + (n << 4) + l15;
    const float bv = bias[g * HDIM + ncol];
#pragma unroll
    for (int m = 0; m < 4; ++m)
#pragma unroll
      for (int j = 0; j < 4; ++j) {
        const int rl = wm + (m << 4) + rq + j;
        if (rl < nrows) {
          const int tok = perm[off + (mt << 7) + rl];
          Yout[((size_t)tok << 9) + ncol] = acc[m][n][j] + bv;
        }
      }
  }
}

extern "C" void kernel_launch(void* const* d_in, const int* in_sizes, int n_in,
                              void* d_out, int out_size, void* d_ws,
                              size_t ws_size, hipStream_t stream) {
  const float* x    = (const float*)d_in[0];
  const int* b_seq  = (const int*)d_in[1];
  const float* W1   = (const float*)d_in[2];
  const float* B1   = (const float*)d_in[3];
  const float* W2   = (const float*)d_in[4];
  const float* B2   = (const float*)d_in[5];
  float* out        = (float*)d_out;

  char* ws = (char*)d_ws;
  int* hdr  = (int*)ws;                          // 1 KB header
  int* perm = (int*)(ws + 1024);                 // 64 KB
  __hip_bfloat16* xa  = (__hip_bfloat16*)(ws + 66560);   // frag order
  __hip_bfloat16* W1p = xa + (size_t)MAXMT * 8 * 8192;   // frag order
  __hip_bfloat16* W2p = W1p + (size_t)NEXP * FDIM * HDIM;// frag order
  __hip_bfloat16* Hp  = W2p + (size_t)NEXP * HDIM * FDIM;// frag order

  const int n4 = NTOK * HDIM / 4;

  k_init<<<2048, 256, 0, stream>>>((const int4*)b_seq, b_seq, (float4*)out,
                                   n4, hdr);
  k_fill<<<NTOK / 256, 256, 0, stream>>>(b_seq, hdr, perm);
  k_pack_a<<<MAXMT * 8, 256, 0, stream>>>(x, hdr, perm, xa);
  k_transpose_cvt<<<dim3(FDIM / 64, HDIM / 64, NEXP), 256, 0, stream>>>(
      W1, W1p, HDIM, FDIM);
  k_transpose_cvt<<<dim3(HDIM / 64, FDIM / 64, NEXP), 256, 0, stream>>>(
      W2, W2p, FDIM, HDIM);
  // grids cover worst-case tile counts; blocks past the actual total exit
  k_gemm1<<<2112, 256, 0, stream>>>(hdr, xa, W1p, B1, Hp);
  k_gemm2<<<528, 256, 0, stream>>>(hdr, perm, Hp, W2p, B2, out);
}